// Round 1
// baseline (392.915 us; speedup 1.0000x reference)
//
#include <hip/hip_runtime.h>
#include <hip/hip_bf16.h>

typedef unsigned short ushort_t;
typedef __bf16 bf16x8 __attribute__((ext_vector_type(8)));
typedef float f32x4 __attribute__((ext_vector_type(4)));

typedef const void __attribute__((address_space(1)))* gas1_t;
typedef void __attribute__((address_space(3)))* las3_t;

#define L_SZ 2048
#define DI   2048
#define M_ROWS 4096
#define NC 64
#define TC 32

__device__ __forceinline__ float bf2f(ushort_t u){
  unsigned x = ((unsigned)u) << 16; float f; __builtin_memcpy(&f, &x, 4); return f;
}
__device__ __forceinline__ ushort_t f2bf(float f){
  __hip_bfloat16 h = __float2bfloat16(f);
  ushort_t u; __builtin_memcpy(&u, &h, 2); return u;
}
__device__ __forceinline__ float siluf(float x){ return x / (1.0f + __expf(-x)); }
__device__ __forceinline__ float softplusf(float x){
  return (x > 20.0f) ? x : log1pf(__expf(x));
}

// ---------------- fused prep: all weight transposes + x cast, ONE launch ----
__global__ __launch_bounds__(256) void k_prep(
    const float* __restrict__ W_in, const float* __restrict__ W_delta,
    const float* __restrict__ W_out, const float* __restrict__ W_B,
    const float* __restrict__ W_C, const float* __restrict__ x,
    ushort_t* __restrict__ W_inT, ushort_t* __restrict__ W_bigT,
    ushort_t* __restrict__ W_outT, ushort_t* __restrict__ xb)
{
  int t = blockIdx.x;
  if (t >= 10368){
    size_t i = (size_t)(t - 10368) * 256 + threadIdx.x;
    float4 v = *(const float4*)(x + i * 4);
    ushort_t o[4] = { f2bf(v.x), f2bf(v.y), f2bf(v.z), f2bf(v.w) };
    *(uint2*)(xb + i * 4) = *(const uint2*)o;
    return;
  }
  const float* in; ushort_t* out; int R, C, tx, ty;
  if (t < 4096)      { in=W_in;    out=W_inT;  R=1024; C=4096; tx = t & 127; ty = t >> 7; }
  else if (t < 8192) { t -= 4096;  in=W_delta; out=W_bigT; R=2048; C=2048; tx = t & 63; ty = t >> 6; }
  else if (t < 10240){ t -= 8192;  in=W_out;   out=W_outT; R=2048; C=1024; tx = t & 31; ty = t >> 5; }
  else if (t < 10304){ t -= 10240; in=W_B;  out=W_bigT + (size_t)2048*2048; R=2048; C=16; tx=0; ty=t; }
  else               { t -= 10304; in=W_C;  out=W_bigT + (size_t)2064*2048; R=2048; C=16; tx=0; ty=t; }
  __shared__ ushort_t tile[32][33];
  int c0 = tx * 32, r0 = ty * 32;
  int xx = threadIdx.x & 31, yy = threadIdx.x >> 5;
  #pragma unroll
  for (int i = 0; i < 32; i += 8){
    int r = r0 + yy + i, c = c0 + xx;
    if (r < R && c < C) tile[yy + i][xx] = f2bf(in[(size_t)r * C + c]);
  }
  __syncthreads();
  #pragma unroll
  for (int i = 0; i < 32; i += 8){
    int c = c0 + yy + i, r = r0 + xx;
    if (r < R && c < C) out[(size_t)c * R + r] = tile[xx][yy + i];
  }
}

// ---------------- legacy GEMM (kept for GEMM3: small N) ----------------
template<int BM, int BN, int EPI>
__global__ __launch_bounds__(256) void k_gemm_bt(
    const ushort_t* __restrict__ A, int lda,
    const ushort_t* __restrict__ Bt, int ldb,
    void* __restrict__ Cout, int ldc,
    const float* __restrict__ bias,
    float* __restrict__ Bm, float* __restrict__ Cm, int K)
{
  constexpr int WM = BM/2, WN = BN/2;
  constexpr int MT = WM/16, NT = WN/16;
  constexpr int ACH = BM*16;
  constexpr int BCH = BN*16;
  constexpr int NISSUE = (ACH+BCH)/256;
  __shared__ __align__(16) char lds[(BM+BN)*256];
  char* ldsA = lds;
  char* ldsB = lds + BM*256;
  const int tid  = threadIdx.x;
  const int wave = tid >> 6, lane = tid & 63;
  const int quad = lane >> 4, l16 = lane & 15;
  const int m_blk = blockIdx.y * BM, n_blk = blockIdx.x * BN;
  const int wm = (wave >> 1) * WM, wn = (wave & 1) * WN;

  f32x4 acc[MT][NT] = {};

  const ushort_t* gptr[NISSUE];
  char* lptr[NISSUE];
  #pragma unroll
  for (int i = 0; i < NISSUE; i++){
    int g = tid + i*256;
    if (g < ACH){
      int sl = (g >= ACH/2) ? 1 : 0;
      int gl = g - sl*(ACH/2);
      int row = gl >> 3, c = gl & 7;
      gptr[i] = A + (size_t)(m_blk + row) * lda + sl*64 + ((c ^ (row & 7)) * 8);
    } else {
      int gb = g - ACH;
      int sl = (gb >= BCH/2) ? 1 : 0;
      int gl = gb - sl*(BCH/2);
      int row = gl >> 3, c = gl & 7;
      gptr[i] = Bt + (size_t)(n_blk + row) * ldb + sl*64 + ((c ^ (row & 7)) * 8);
    }
    lptr[i] = lds + (size_t)g*16;
  }

  const int xsw = (l16 & 7);

  for (int k0 = 0; k0 < K; k0 += 128){
    #pragma unroll
    for (int i = 0; i < NISSUE; i++)
      __builtin_amdgcn_global_load_lds((gas1_t)(const void*)(gptr[i] + k0), (las3_t)lptr[i], 16, 0, 0);
    __syncthreads();
    #pragma unroll
    for (int sl = 0; sl < 2; sl++){
      #pragma unroll
      for (int s = 0; s < 2; s++){
        const int xa = ((s*4 + quad) ^ xsw) * 16;
        bf16x8 af[MT], bfr[NT];
        #pragma unroll
        for (int i = 0; i < MT; i++)
          af[i]  = *(const bf16x8*)(ldsA + sl*(BM*128) + (wm + i * 16 + l16) * 128 + xa);
        #pragma unroll
        for (int i = 0; i < NT; i++)
          bfr[i] = *(const bf16x8*)(ldsB + sl*(BN*128) + (wn + i * 16 + l16) * 128 + xa);
        #pragma unroll
        for (int mt = 0; mt < MT; mt++)
          #pragma unroll
          for (int nt = 0; nt < NT; nt++)
            acc[mt][nt] = __builtin_amdgcn_mfma_f32_16x16x32_bf16(af[mt], bfr[nt], acc[mt][nt], 0, 0, 0);
      }
    }
    __syncthreads();
  }

  #pragma unroll
  for (int mt = 0; mt < MT; mt++){
    #pragma unroll
    for (int nt = 0; nt < NT; nt++){
      #pragma unroll
      for (int r = 0; r < 4; r++){
        int m = m_blk + wm + mt * 16 + quad * 4 + r;
        int n = n_blk + wn + nt * 16 + l16;
        float v = acc[mt][nt][r];
        if (EPI == 0){
          ((float*)Cout)[(size_t)m * ldc + n] = v;
        } else if (EPI == 1){
          ((__hip_bfloat16*)Cout)[(size_t)m * ldc + n] = __float2bfloat16(siluf(v));
        } else {
          if (n < 2048)      ((ushort_t*)Cout)[(size_t)m * ldc + n] = f2bf(softplusf(v + bias[n]));
          else if (n < 2064) Bm[(size_t)m * 16 + (n - 2048)] = v;
          else if (n < 2080) Cm[(size_t)m * 16 + (n - 2064)] = v;
        }
      }
    }
  }
}

// ---------------- 256x256 8-phase GEMM (T2+T3+T4+T5 template) ----------------
// C[M,N] = A[M,K] * Bt[N,K]^T, BK=64, 8 waves (512 thr), LDS 128 KiB
// (2 dbuf x (A:32KB rows0..255 x 128B) + (B:32KB)), XOR-swizzled via
// pre-swizzled global source + swizzled ds_read (both-sides, m201 pattern).
// Phase = one (A-half x B-half) quadrant (128x128 of C): 8 waves as 2x4,
// each wave 64x32 -> 16 MFMA/phase. Quadrant order Q00,Q10,Q01,Q11 makes
// halves die progressively: B0@p2, A0@p3, A1/B1@p4 -> each phase re-stages
// exactly one dead half of tile T+1/T+2/T+3. vmcnt(4) only at p4/p8.

#define STG_A(d,H,T) { \
  __builtin_amdgcn_global_load_lds((gas1_t)(const void*)(gA + (size_t)(H)*128*lda + (size_t)(T)*64), \
      (las3_t)(void*)(lds + (d)*65536 + (H)*16384 + tid*16), 16, 0, 0); \
  __builtin_amdgcn_global_load_lds((gas1_t)(const void*)(gA + ((size_t)(H)*128+64)*lda + (size_t)(T)*64), \
      (las3_t)(void*)(lds + (d)*65536 + (H)*16384 + 8192 + tid*16), 16, 0, 0); }

#define STG_B(d,H,T) { \
  __builtin_amdgcn_global_load_lds((gas1_t)(const void*)(gB + (size_t)(H)*128*ldb + (size_t)(T)*64), \
      (las3_t)(void*)(lds + (d)*65536 + 32768 + (H)*16384 + tid*16), 16, 0, 0); \
  __builtin_amdgcn_global_load_lds((gas1_t)(const void*)(gB + ((size_t)(H)*128+64)*ldb + (size_t)(T)*64), \
      (las3_t)(void*)(lds + (d)*65536 + 32768 + (H)*16384 + 8192 + tid*16), 16, 0, 0); }

// phase: ds-read quadrant frags | stage one half | bar | lgkmcnt(0) |
//        setprio(1) 16 MFMA setprio(0)   (trailing barrier added at call site)
#define PHASE(d, qm, qn, ...) { \
  bf16x8 af0[4], af1[4], bq0[2], bq1[2]; \
  const char* pA_ = lds + (d)*65536 + ((qm)*128 + wm*64 + l16)*128; \
  const char* pB_ = lds + (d)*65536 + 32768 + ((qn)*128 + wn*32 + l16)*128; \
  const int x0_ = ((0*4 + quad) ^ xsw) * 16; \
  const int x1_ = ((1*4 + quad) ^ xsw) * 16; \
  _Pragma("unroll") \
  for (int mt = 0; mt < 4; mt++){ \
    af0[mt] = *(const bf16x8*)(pA_ + mt*2048 + x0_); \
    af1[mt] = *(const bf16x8*)(pA_ + mt*2048 + x1_); } \
  _Pragma("unroll") \
  for (int nt = 0; nt < 2; nt++){ \
    bq0[nt] = *(const bf16x8*)(pB_ + nt*2048 + x0_); \
    bq1[nt] = *(const bf16x8*)(pB_ + nt*2048 + x1_); } \
  __VA_ARGS__ \
  __builtin_amdgcn_s_barrier(); \
  asm volatile("s_waitcnt lgkmcnt(0)" ::: "memory"); \
  __builtin_amdgcn_sched_barrier(0); \
  __builtin_amdgcn_s_setprio(1); \
  _Pragma("unroll") \
  for (int mt = 0; mt < 4; mt++){ \
    _Pragma("unroll") \
    for (int nt = 0; nt < 2; nt++){ \
      acc[qm][qn][mt][nt] = __builtin_amdgcn_mfma_f32_16x16x32_bf16(af0[mt], bq0[nt], acc[qm][qn][mt][nt], 0, 0, 0); \
      acc[qm][qn][mt][nt] = __builtin_amdgcn_mfma_f32_16x16x32_bf16(af1[mt], bq1[nt], acc[qm][qn][mt][nt], 0, 0, 0); } } \
  __builtin_amdgcn_s_setprio(0); }

#define TBAR __builtin_amdgcn_s_barrier()

template<int EPI>
__global__ __launch_bounds__(512, 2) void k_gemm256(
    const ushort_t* __restrict__ A, int lda,
    const ushort_t* __restrict__ Bt, int ldb,
    void* __restrict__ Cout, int ldc,
    const float* __restrict__ bias,
    float* __restrict__ Bm, float* __restrict__ Cm, int K)
{
  __shared__ __align__(16) char lds[131072];
  const int tid  = threadIdx.x;
  const int wave = tid >> 6, lane = tid & 63;
  const int quad = lane >> 4, l16 = lane & 15;
  const int wm = wave >> 2;          // 0..1 : 64-row slice within quadrant
  const int wn = wave & 3;           // 0..3 : 32-col slice within quadrant
  const int m_blk = blockIdx.y * 256, n_blk = blockIdx.x * 256;
  const int xsw = l16 & 7;

  // staging coords: 512 thr x 16B = 64 rows x 128B per issue, 2 issues/half
  const int srow = tid >> 3;         // 0..63
  const int schk = tid & 7;
  const ushort_t* gA = A  + (size_t)(m_blk + srow) * lda + ((schk ^ (srow & 7)) * 8);
  const ushort_t* gB = Bt + (size_t)(n_blk + srow) * ldb + ((schk ^ (srow & 7)) * 8);

  f32x4 acc[2][2][4][2] = {};        // [qm][qn][mt][nt] = 128 VGPRs

  const int NTK = K >> 6;            // K-tiles of 64 (even; >= 16 here)

  // prologue: tile0 {A0,B0,A1,B1} -> buf0 ; tile1 {B0,A0} -> buf1
  STG_A(0,0,0); STG_B(0,0,0); STG_A(0,1,0); STG_B(0,1,0);
  STG_B(1,0,1); STG_A(1,0,1);
  asm volatile("s_waitcnt vmcnt(4)" ::: "memory");   // tile0 fully landed
  __builtin_amdgcn_s_barrier();

  for (int T = 0; T < NTK; T += 2){
    // ---- tile T from buf0 ----
    PHASE(0,0,0, STG_A(1,1,T+1);) TBAR;                          // p1 Q00; stage (T+1).A1
    PHASE(0,1,0, STG_B(1,1,T+1);) TBAR;                          // p2 Q10; stage (T+1).B1
    PHASE(0,0,1, if (T+2 < NTK) STG_B(0,0,T+2);) TBAR;           // p3 Q01; stage (T+2).B0
    PHASE(0,1,1, if (T+2 < NTK) STG_A(0,0,T+2);)                 // p4 Q11; stage (T+2).A0
    if (T+2 < NTK) { asm volatile("s_waitcnt vmcnt(4)" ::: "memory"); }
    else           { asm volatile("s_waitcnt vmcnt(0)" ::: "memory"); }
    TBAR;
    // ---- tile T+1 from buf1 ----
    PHASE(1,0,0, if (T+2 < NTK) STG_A(0,1,T+2);) TBAR;           // p5 Q00; stage (T+2).A1
    PHASE(1,1,0, if (T+2 < NTK) STG_B(0,1,T+2);) TBAR;           // p6 Q10; stage (T+2).B1
    PHASE(1,0,1, if (T+3 < NTK) STG_B(1,0,T+3);) TBAR;           // p7 Q01; stage (T+3).B0
    PHASE(1,1,1, if (T+3 < NTK) STG_A(1,0,T+3);)                 // p8 Q11; stage (T+3).A0
    asm volatile("s_waitcnt vmcnt(4)" ::: "memory");
    TBAR;
  }

  #pragma unroll
  for (int qm = 0; qm < 2; qm++){
    #pragma unroll
    for (int qn = 0; qn < 2; qn++){
      #pragma unroll
      for (int mt = 0; mt < 4; mt++){
        #pragma unroll
        for (int nt = 0; nt < 2; nt++){
          #pragma unroll
          for (int r = 0; r < 4; r++){
            int m = m_blk + qm*128 + wm*64 + mt*16 + quad*4 + r;
            int n = n_blk + qn*128 + wn*32 + nt*16 + l16;
            float v = acc[qm][qn][mt][nt][r];
            if (EPI == 1){
              ((__hip_bfloat16*)Cout)[(size_t)m * ldc + n] = __float2bfloat16(siluf(v));
            } else {
              if (n < 2048)      ((ushort_t*)Cout)[(size_t)m * ldc + n] = f2bf(softplusf(v + bias[n]));
              else if (n < 2064) Bm[(size_t)m * 16 + (n - 2048)] = v;
              else if (n < 2080) Cm[(size_t)m * 16 + (n - 2064)] = v;
            }
          }
        }
      }
    }
  }
}

__device__ __forceinline__ void load_An(const float* A_log, int d, float* An){
  const float* ap = A_log + (size_t)d * 16;
  #pragma unroll
  for (int j = 0; j < 16; j += 4){
    float4 v = *(const float4*)(ap + j);
    An[j]   = -__expf(v.x);
    An[j+1] = -__expf(v.y);
    An[j+2] = -__expf(v.z);
    An[j+3] = -__expf(v.w);
  }
}

// ---------------- scan pass 1: per-chunk partials (h_in = 0) ----------------
__global__ __launch_bounds__(256) void k_scan1(
    const ushort_t* __restrict__ delta, const ushort_t* __restrict__ U,
    const float* __restrict__ Bm, const float* __restrict__ A_log,
    float* __restrict__ q, float* __restrict__ S)
{
  __shared__ float ldsB[TC * 16];
  const int tid = threadIdx.x;
  const int ch  = blockIdx.x * 256 + tid;
  const int b   = ch >> 11, d = ch & 2047;
  const int c   = blockIdx.y;
  const int t0  = c * TC;
  if (tid < 128){
    int tt = tid >> 2, n4 = (tid & 3) * 4;
    *(float4*)&ldsB[tt * 16 + n4] = *(const float4*)&Bm[((size_t)b * L_SZ + t0 + tt) * 16 + n4];
  }
  float An[16];
  load_An(A_log, d, An);
  __syncthreads();
  float h[16];
  #pragma unroll
  for (int j = 0; j < 16; j++) h[j] = 0.f;
  float Ssum = 0.f;
  const size_t row0 = (size_t)b * L_SZ + t0;
  for (int ti = 0; ti < TC; ti += 4){
    float dlt[4], uv[4];
    #pragma unroll
    for (int k = 0; k < 4; k++){
      size_t row = row0 + ti + k;
      dlt[k] = bf2f(delta[row * DI + d]);
      uv[k]  = bf2f(U[row * 4096 + d]);
    }
    #pragma unroll
    for (int k = 0; k < 4; k++){
      float du = dlt[k] * uv[k];
      Ssum += dlt[k];
      #pragma unroll
      for (int nn = 0; nn < 16; nn++)
        h[nn] = fmaf(__expf(dlt[k] * An[nn]), h[nn], du * ldsB[(ti + k) * 16 + nn]);
    }
  }
  size_t qb = ((size_t)c * M_ROWS + ch) * 16;
  #pragma unroll
  for (int j = 0; j < 16; j += 4)
    *(float4*)&q[qb + j] = make_float4(h[j], h[j+1], h[j+2], h[j+3]);
  S[(size_t)c * M_ROWS + ch] = Ssum;
}

// ---------------- scan combine: sequential over chunks ----------------
__global__ __launch_bounds__(256) void k_scan_combine(
    const float* __restrict__ q, const float* __restrict__ S,
    const float* __restrict__ A_log, float* __restrict__ hin)
{
  int gid = blockIdx.x * 256 + threadIdx.x;      // 65536 = 4096 ch * 16 n
  int ch = gid >> 4, nn = gid & 15, d = ch & 2047;
  float An = -__expf(A_log[(size_t)d * 16 + nn]);
  float h = 0.f;
  for (int c = 0; c < NC; c++){
    size_t base = (size_t)c * M_ROWS + ch;
    hin[base * 16 + nn] = h;
    h = fmaf(__expf(An * S[base]), h, q[base * 16 + nn]);
  }
}

// ---------------- scan pass 2: replay with h_in, emit y ----------------
__global__ __launch_bounds__(256) void k_scan2(
    const ushort_t* __restrict__ delta, const ushort_t* __restrict__ U,
    const float* __restrict__ Bm, const float* __restrict__ Cm,
    const float* __restrict__ A_log, const float* __restrict__ Dpar,
    const float* __restrict__ hin, ushort_t* __restrict__ Y)
{
  __shared__ float ldsBC[TC * 16 * 2];
  const int tid = threadIdx.x;
  const int ch  = blockIdx.x * 256 + tid;
  const int b   = ch >> 11, d = ch & 2047;
  const int c   = blockIdx.y;
  const int t0  = c * TC;
  {
    int tt = tid >> 3, n2 = (tid & 7) * 2;
    size_t gb = ((size_t)b * L_SZ + t0 + tt) * 16 + n2;
    float2 bv = *(const float2*)&Bm[gb];
    float2 cv = *(const float2*)&Cm[gb];
    float2* dst = (float2*)&ldsBC[(tt * 16 + n2) * 2];
    dst[0] = make_float2(bv.x, cv.x);
    dst[1] = make_float2(bv.y, cv.y);
  }
  float An[16];
  load_An(A_log, d, An);
  float Dv = Dpar[d];
  __syncthreads();
  float h[16];
  size_t hb = ((size_t)c * M_ROWS + ch) * 16;
  #pragma unroll
  for (int j = 0; j < 16; j += 4){
    float4 hv = *(const float4*)&hin[hb + j];
    h[j] = hv.x; h[j+1] = hv.y; h[j+2] = hv.z; h[j+3] = hv.w;
  }
  const size_t row0 = (size_t)b * L_SZ + t0;
  for (int ti = 0; ti < TC; ti += 4){
    float dlt[4], uv[4], sres[4];
    #pragma unroll
    for (int k = 0; k < 4; k++){
      size_t row = row0 + ti + k;
      dlt[k]  = bf2f(delta[row * DI + d]);
      uv[k]   = bf2f(U[row * 4096 + d]);
      sres[k] = bf2f(U[row * 4096 + 2048 + d]);
    }
    ushort_t yo[4];
    #pragma unroll
    for (int k = 0; k < 4; k++){
      float du = dlt[k] * uv[k];
      float y = 0.f;
      #pragma unroll
      for (int nn = 0; nn < 16; nn++){
        float2 bc = *(const float2*)&ldsBC[((ti + k) * 16 + nn) * 2];
        h[nn] = fmaf(__expf(dlt[k] * An[nn]), h[nn], du * bc.x);
        y = fmaf(h[nn], bc.y, y);
      }
      yo[k] = f2bf((y + uv[k] * Dv) * sres[k]);
    }
    #pragma unroll
    for (int k = 0; k < 4; k++)
      Y[(row0 + ti + k) * DI + d] = yo[k];
  }
}

extern "C" void kernel_launch(void* const* d_in, const int* in_sizes, int n_in,
                              void* d_out, int out_size, void* d_ws, size_t ws_size,
                              hipStream_t stream)
{
  const float* x       = (const float*)d_in[0];
  const float* W_in    = (const float*)d_in[1];
  const float* W_delta = (const float*)d_in[2];
  const float* b_delta = (const float*)d_in[3];
  const float* W_B     = (const float*)d_in[4];
  const float* W_C     = (const float*)d_in[5];
  const float* A_log   = (const float*)d_in[6];
  const float* D_par   = (const float*)d_in[7];
  const float* W_out   = (const float*)d_in[8];

  char* ws = (char*)d_ws;
  size_t off = 0;
  auto alloc = [&](size_t bytes){ char* p = ws + off; off += (bytes + 255) & ~(size_t)255; return p; };
  ushort_t* W_inT  = (ushort_t*)alloc((size_t)4096*1024*2);
  ushort_t* W_bigT = (ushort_t*)alloc((size_t)2304*2048*2);   // 2304 N-rows: 9x256 tiles
  ushort_t* W_outT = (ushort_t*)alloc((size_t)1024*2048*2);
  ushort_t* xb     = (ushort_t*)alloc((size_t)4096*1024*2);
  ushort_t* U      = (ushort_t*)alloc((size_t)4096*4096*2);
  ushort_t* dl     = (ushort_t*)alloc((size_t)4096*2048*2);
  float*    Bm     = (float*)alloc((size_t)4096*16*4);
  float*    Cm     = (float*)alloc((size_t)4096*16*4);
  float*    qbuf   = (float*)alloc((size_t)NC*4096*16*4);
  float*    Sbuf   = (float*)alloc((size_t)NC*4096*4);
  float*    hin    = (float*)alloc((size_t)NC*4096*16*4);
  ushort_t* Y      = (ushort_t*)alloc((size_t)4096*2048*2);

  // 1) fused prep
  k_prep<<<dim3(14464),256,0,stream>>>(W_in, W_delta, W_out, W_B, W_C, x,
                                       W_inT, W_bigT, W_outT, xb);

  // 2) GEMM1: U = silu(x @ W_in)  — 256x256 8-phase, grid 16x16 = 256 blocks
  k_gemm256<1><<<dim3(16,16),512,0,stream>>>(xb, 1024, W_inT, 1024, U, 4096,
                                             nullptr, nullptr, nullptr, 1024);

  // 3) GEMM2 (padded-N fusion): dl = softplus(u@W_delta+b) [bf16], Bm/Cm fused
  //    N padded 2080 -> 2304 (9 N-blocks); cols >= 2080 discarded in epilogue
  k_gemm256<2><<<dim3(9,16),512,0,stream>>>(U, 4096, W_bigT, 2048, dl, 2048,
                                            b_delta, Bm, Cm, 2048);

  // 4-6) chunked selective scan
  k_scan1<<<dim3(16,NC),256,0,stream>>>(dl, U, Bm, A_log, qbuf, Sbuf);
  k_scan_combine<<<dim3(256),256,0,stream>>>(qbuf, Sbuf, A_log, hin);
  k_scan2<<<dim3(16,NC),256,0,stream>>>(dl, U, Bm, Cm, A_log, D_par, hin, Y);

  // 7) GEMM3: out = Y @ W_out (fp32 output) — small N, keep legacy kernel
  k_gemm_bt<64,64,0><<<dim3(16,64),256,0,stream>>>(Y, 2048, W_outT, 2048, d_out, 1024,
                                                   nullptr, nullptr, nullptr, 2048);
}